// Round 13
// baseline (55.999 us; speedup 1.0000x reference)
//
#include <hip/hip_runtime.h>
#include <hip/hip_fp16.h>
#include <math.h>

#define SEQ 250
#define ST  252      // padded t-stride: rows 16B-aligned (ST*4 = 1008 = 63*16)
#define NCLS 12

typedef __attribute__((ext_vector_type(4))) _Float16 half4v;
typedef __attribute__((ext_vector_type(4))) float    float4v;

// Butterfly add via DPP (zero DS-pipe ops).
// 0xB1=quad_perm xor1; 0x4E=quad_perm xor2; 0x141=row_half_mirror (lane^7,
// valid once quad-constant); 0x140=row_mirror (lane^15, once 8-group-constant).
template<int CTRL>
__device__ __forceinline__ float dpp_add(float v) {
    int t = __builtin_amdgcn_update_dpp(0, __float_as_int(v), CTRL, 0xF, 0xF, true);
    return v + __int_as_float(t);
}

__device__ __forceinline__ __half2 f_as_h2(float f) {
    union { float f; __half2 h; } u; u.f = f; return u.h;
}
__device__ __forceinline__ float h2_as_f(__half2 h) {
    union { __half2 h; float f; } u; u.h = h; return u.f;
}

// 512 threads, TWO batch elements per block.
// LDS: 2 x (s_bc 16128 + s_dlu 16128 + s_sz 8064) = 80,640 B -> 2 blocks/CU.
// r4-r6: no register live ranges across the scan (spills -> 45 MB scratch).
// r11: issue-bound on total inst volume -> matrix pipe takes the projections.
// r12 lesson: measured inst stream ~2.5x idealized audit -> the fat is in
// scalar-LDS phase loops; ph1 goes MFMA (like ph3), ph2 goes b128.
__global__ __launch_bounds__(512)
void mamba_cls_kernel(
    const float* __restrict__ x,         // (B, 8, 250)
    const float* __restrict__ in_proj_w, // (32, 8)
    const float* __restrict__ conv_w,    // (16, 4)
    const float* __restrict__ conv_b,    // (16)
    const float* __restrict__ x_proj_w,  // (33, 16)
    const float* __restrict__ dt_proj_w, // (16, 1)
    const float* __restrict__ dt_proj_b, // (16)
    const float* __restrict__ A_log,     // (16, 16)
    const float* __restrict__ Dp,        // (16)
    const float* __restrict__ out_proj_w,// (8, 16)
    const float* __restrict__ fc_w,      // (12, 2000)
    const float* __restrict__ fc_b,      // (12)
    float* __restrict__ out)             // (B, 12)
{
    // Per problem p:
    // s_bc [p]: ph1-2 x_in (f32 view [d*ST+t]); ph3+ {B,C} half2 [s*ST+t];
    //           ph5b+ out2000 (f32 view [t*8+j])
    // s_dlu   : ph0-1 staged x of BOTH problems (flat f32 from s_dlu[0]);
    //           ph2+ {dl,u} half2 [d*ST+t] (u=.y ph2, dl=.x ph3);
    //           ph4+ y (f32, same word); ph6 reduce partials
    // s_sz [p]: silu(z) fp16 [d*ST+t]
    __shared__ __align__(16) __half2 s_bc [2][16 * ST];
    __shared__ __align__(16) __half2 s_dlu[2][16 * ST];
    __shared__ __align__(16) __half  s_sz [2][16 * ST];

    const int tid  = threadIdx.x;
    const int p    = tid >> 8;
    const int tid8 = tid & 255;
    const int b0   = blockIdx.x * 2;

    // ---- Phase 0: stage x for BOTH problems coalesced (float4)
    {
        float4* s_xf4 = (float4*)s_dlu[0];
        const float4* __restrict__ xb4 =
            (const float4*)(x + (size_t)b0 * (8 * SEQ));
        for (int i = tid; i < 1000; i += 512) s_xf4[i] = xb4[i];
    }
    __syncthreads();

    // ---- Phase 1 (MFMA): per 16-t tile, x_in = x@Wx^T and z = x@Wz^T via
    // v_mfma_f32_16x16x16f16 (K=8 padded to 16 with B=0 cols; A k>=8 values
    // are don't-cares since B is exactly 0 there). D: col=l&15 (d), row =
    // 4*(l>>4)+r (t_local) -> b128 x_in write + b64 sz write per lane.
    {
        const int l    = tid8 & 63;
        const int rowc = l & 15;          // A-row (t_local) AND D-col (d)
        const int kg   = l >> 4;
        const int wave = tid8 >> 6;
        half4v wX, wZ;
        #pragma unroll
        for (int i = 0; i < 4; ++i) {
            int k = 4 * kg + i;
            wX[i] = (k < 8) ? (_Float16)in_proj_w[rowc * 8 + k] : (_Float16)0.f;
            wZ[i] = (k < 8) ? (_Float16)in_proj_w[(16 + rowc) * 8 + k] : (_Float16)0.f;
        }
        const float* s_xf = (const float*)s_dlu[0] + p * (8 * SEQ);
        float* s_f = (float*)s_bc[p];
        __half* szp = (__half*)s_sz[p];
        const float4v zero4 = {0.f, 0.f, 0.f, 0.f};
        const int ksafe = 4 * (kg & 1);   // valid channel base for ALL lanes
        for (int tile = wave; tile < 16; tile += 4) {
            const int t0 = tile * 16;
            half4v A;
            #pragma unroll
            for (int i = 0; i < 4; ++i)
                A[i] = (_Float16)s_xf[(ksafe + i) * SEQ + t0 + rowc];
            float4v dX = __builtin_amdgcn_mfma_f32_16x16x16f16(A, wX, zero4, 0, 0, 0);
            float4v dZ = __builtin_amdgcn_mfma_f32_16x16x16f16(A, wZ, zero4, 0, 0, 0);
            const int tb = t0 + kg * 4;
            if (tb <= 248) {              // words tb..tb+3 <= 251 (pad ok)
                float4 xw;
                xw.x = dX[0]; xw.y = dX[1]; xw.z = dX[2]; xw.w = dX[3];
                *reinterpret_cast<float4*>(s_f + rowc * ST + tb) = xw;
                float sz0 = dZ[0] / (1.f + __expf(-dZ[0]));
                float sz1 = dZ[1] / (1.f + __expf(-dZ[1]));
                float sz2 = dZ[2] / (1.f + __expf(-dZ[2]));
                float sz3 = dZ[3] / (1.f + __expf(-dZ[3]));
                float2 zw;
                zw.x = h2_as_f(__floats2half2_rn(sz0, sz1));
                zw.y = h2_as_f(__floats2half2_rn(sz2, sz3));
                *reinterpret_cast<float2*>(szp + rowc * ST + tb) = zw;
            }
        }
    }
    __syncthreads();

    // ---- Phase 2: causal conv(k=4)+SiLU -> u, 4t per chunk: two b128 window
    // reads + one b128 write of whole {0,u} words (dl slot filled by ph3).
    {
        const int d  = tid8 & 15;
        const int c0 = (tid8 >> 4) * 4;
        float cw[4];
        #pragma unroll
        for (int k = 0; k < 4; ++k) cw[k] = conv_w[d * 4 + k];
        const float cb = conv_b[d];
        const float* s_f = (const float*)s_bc[p] + d * ST;
        __half2* dluw = s_dlu[p] + d * ST;
        const __half hz = __float2half(0.f);
        for (int t0 = c0; t0 < SEQ; t0 += 64) {
            float w[8];
            if (t0 == 0) {
                w[0] = 0.f; w[1] = 0.f; w[2] = 0.f; w[3] = 0.f;
            } else {
                float4 a = *reinterpret_cast<const float4*>(s_f + t0 - 4);
                w[0] = a.x; w[1] = a.y; w[2] = a.z; w[3] = a.w;
            }
            float4 bv = *reinterpret_cast<const float4*>(s_f + t0);
            w[4] = bv.x; w[5] = bv.y; w[6] = bv.z; w[7] = bv.w;
            float4 uw;
            #pragma unroll
            for (int j = 0; j < 4; ++j) {
                float acc = cb;
                #pragma unroll
                for (int k = 0; k < 4; ++k) acc = fmaf(cw[k], w[j + k + 1], acc);
                float sg = 1.f / (1.f + __expf(-acc));
                ((float*)&uw)[j] = h2_as_f(__halves2half2(hz, __float2half(acc * sg)));
            }
            *reinterpret_cast<float4*>(dluw + t0) = uw;
        }
    }
    __syncthreads();

    // ---- Phase 3 (MFMA): per 16-t tile, D = u(16t x 16d) * W(16d x 16col)
    // via v_mfma_f32_16x16x16f16 (same fragment map as ph1; verified r12).
    {
        const int wave = tid8 >> 6;       // 0..3
        const int l    = tid8 & 63;
        const int rowc = l & 15;          // A-row (t_local) AND D-col (state)
        const int kg   = l >> 4;          // k-group

        half4v wB, wC, wD;
        #pragma unroll
        for (int i = 0; i < 4; ++i) {
            wB[i] = (_Float16)x_proj_w[(1  + rowc) * 16 + 4 * kg + i];
            wC[i] = (_Float16)x_proj_w[(17 + rowc) * 16 + 4 * kg + i];
            wD[i] = (_Float16)x_proj_w[4 * kg + i];
        }
        const float dtw_c = dt_proj_w[rowc];
        const float dtb_c = dt_proj_b[rowc];
        const float4v zero4 = {0.f, 0.f, 0.f, 0.f};
        const unsigned int* __restrict__ dlu_w = (const unsigned int*)s_dlu[p];

        for (int tile = wave; tile < 16; tile += 4) {
            const int t0 = tile * 16;
            // A-frag: u[t0+rowc][4kg+i] = high half of {dl,u} word
            unsigned int w0 = dlu_w[(4 * kg + 0) * ST + t0 + rowc];
            unsigned int w1 = dlu_w[(4 * kg + 1) * ST + t0 + rowc];
            unsigned int w2 = dlu_w[(4 * kg + 2) * ST + t0 + rowc];
            unsigned int w3 = dlu_w[(4 * kg + 3) * ST + t0 + rowc];
            union { unsigned int u[2]; half4v h; } A;
            A.u[0] = (w0 >> 16) | (w1 & 0xFFFF0000u);
            A.u[1] = (w2 >> 16) | (w3 & 0xFFFF0000u);

            float4v dB = __builtin_amdgcn_mfma_f32_16x16x16f16(A.h, wB, zero4, 0, 0, 0);
            float4v dC = __builtin_amdgcn_mfma_f32_16x16x16f16(A.h, wC, zero4, 0, 0, 0);
            float4v dT = __builtin_amdgcn_mfma_f32_16x16x16f16(A.h, wD, zero4, 0, 0, 0);

            const int tb = t0 + kg * 4;   // first of this lane's 4 t's
            if (tb <= 248) {              // words tb..tb+3 <= 251 (pad ok)
                __half2 h0 = __floats2half2_rn(dB[0], dC[0]);
                __half2 h1 = __floats2half2_rn(dB[1], dC[1]);
                __half2 h2 = __floats2half2_rn(dB[2], dC[2]);
                __half2 h3 = __floats2half2_rn(dB[3], dC[3]);
                float4 wv;
                wv.x = h2_as_f(h0); wv.y = h2_as_f(h1);
                wv.z = h2_as_f(h2); wv.w = h2_as_f(h3);
                *reinterpret_cast<float4*>(s_bc[p] + rowc * ST + tb) = wv;
            }
            #pragma unroll
            for (int r = 0; r < 4; ++r) {
                int t = tb + r;
                if (t < SEQ) {
                    float v  = fmaf(dT[r], dtw_c, dtb_c);
                    float dl = (v > 20.f) ? v : __logf(1.f + __expf(v));
                    s_dlu[p][rowc * ST + t].x = __float2half(dl);
                }
            }
        }
    }
    __syncthreads();

    // ---- Phase 4: scan, s-folded x2, b128 per 4 timesteps (1 DS-op/t/wave).
    // Active: tid<256. waves 0-1 -> problem 0, waves 2-3 -> problem 1.
    // d = (tid&127)>>3, s2 = tid&7; states s2 and s2+8.
    if (tid < 256) {
        const int sp   = tid >> 7;
        const int i7   = tid & 127;
        const int d    = i7 >> 3;
        const int s2   = i7 & 7;
        const float A2a = -__expf(A_log[d * 16 + s2])     * 1.4426950408889634f;
        const float A2b = -__expf(A_log[d * 16 + s2 + 8]) * 1.4426950408889634f;
        const float Dd  = Dp[d];
        const __half2* __restrict__ dlu_p = s_dlu[sp] + d * ST;
        const __half2* __restrict__ bca_p = s_bc [sp] + s2 * ST;
        const __half2* __restrict__ bcb_p = s_bc [sp] + (s2 + 8) * ST;
        const __half*  __restrict__ sz_p  = (const __half*)s_sz[sp] + d * ST;
        float* __restrict__ y_p = (float*)s_dlu[sp] + d * ST;
        float ha = 0.f, hb = 0.f;
        for (int t = 0; t < 248; t += 4) {
            float4 duv4 = *reinterpret_cast<const float4*>(dlu_p + t);
            float4 bca4 = *reinterpret_cast<const float4*>(bca_p + t);
            float4 bcb4 = *reinterpret_cast<const float4*>(bcb_p + t);
            float2 sz2  = *reinterpret_cast<const float2*>(sz_p + t);
            float fdu[4] = {duv4.x, duv4.y, duv4.z, duv4.w};
            float fba[4] = {bca4.x, bca4.y, bca4.z, bca4.w};
            float fbb[4] = {bcb4.x, bcb4.y, bcb4.z, bcb4.w};
            float2 szl = __half22float2(f_as_h2(sz2.x));
            float2 szh = __half22float2(f_as_h2(sz2.y));
            float fsz[4] = {szl.x, szl.y, szh.x, szh.y};
            #pragma unroll
            for (int tt = 0; tt < 4; ++tt) {
                float2 du  = __half22float2(f_as_h2(fdu[tt]));
                float2 bca = __half22float2(f_as_h2(fba[tt]));
                float2 bcb = __half22float2(f_as_h2(fbb[tt]));
                float dlu = du.x * du.y;
                ha = fmaf(exp2f(du.x * A2a), ha, dlu * bca.x);
                hb = fmaf(exp2f(du.x * A2b), hb, dlu * bcb.x);
                float r = fmaf(hb, bcb.y, ha * bca.y);
                r = dpp_add<0xB1>(r);
                r = dpp_add<0x4E>(r);
                r = dpp_add<0x141>(r);
                if (s2 == 0) y_p[t + tt] = fmaf(du.y, Dd, r) * fsz[tt];
            }
        }
        {   // tail t = 248, 249
            float2 duv2 = *reinterpret_cast<const float2*>(dlu_p + 248);
            float2 bca2 = *reinterpret_cast<const float2*>(bca_p + 248);
            float2 bcb2 = *reinterpret_cast<const float2*>(bcb_p + 248);
            float2 szf  = __half22float2(*reinterpret_cast<const __half2*>(sz_p + 248));
            float fdu[2] = {duv2.x, duv2.y};
            float fba[2] = {bca2.x, bca2.y};
            float fbb[2] = {bcb2.x, bcb2.y};
            float fsz[2] = {szf.x, szf.y};
            #pragma unroll
            for (int tt = 0; tt < 2; ++tt) {
                float2 du  = __half22float2(f_as_h2(fdu[tt]));
                float2 bca = __half22float2(f_as_h2(fba[tt]));
                float2 bcb = __half22float2(f_as_h2(fbb[tt]));
                float dlu = du.x * du.y;
                ha = fmaf(exp2f(du.x * A2a), ha, dlu * bca.x);
                hb = fmaf(exp2f(du.x * A2b), hb, dlu * bcb.x);
                float r = fmaf(hb, bcb.y, ha * bca.y);
                r = dpp_add<0xB1>(r);
                r = dpp_add<0x4E>(r);
                r = dpp_add<0x141>(r);
                if (s2 == 0) y_p[248 + tt] = fmaf(du.y, Dd, r) * fsz[tt];
            }
        }
    }
    __syncthreads();

    // ---- Phase 5b: out2000[t*8+j] = sum_d y[d,t]*out_proj_w[j,d]
    // Mapping: j = tid8&7, 4t-chunk = tid8>>3; y read as b128 per d-row.
    {
        float* s_f  = (float*)s_bc[p];
        const float* s_yf = (const float*)s_dlu[p];
        const int j = tid8 & 7;
        float w[16];
        #pragma unroll
        for (int d2 = 0; d2 < 16; ++d2) w[d2] = out_proj_w[j * 16 + d2];
        for (int t0 = (tid8 >> 3) * 4; t0 < SEQ; t0 += 128) {
            float a0 = 0.f, a1 = 0.f, a2 = 0.f, a3 = 0.f;
            #pragma unroll
            for (int d2 = 0; d2 < 16; ++d2) {
                float4 y4 = *reinterpret_cast<const float4*>(s_yf + d2 * ST + t0);
                a0 = fmaf(w[d2], y4.x, a0);
                a1 = fmaf(w[d2], y4.y, a1);
                a2 = fmaf(w[d2], y4.z, a2);
                a3 = fmaf(w[d2], y4.w, a3);
            }
            s_f[(t0 + 0) * 8 + j] = a0;
            s_f[(t0 + 1) * 8 + j] = a1;
            if (t0 + 2 < SEQ) s_f[(t0 + 2) * 8 + j] = a2;
            if (t0 + 3 < SEQ) s_f[(t0 + 3) * 8 + j] = a3;
        }
    }
    __syncthreads();

    // ---- Phase 6: logits[c] = out2000 . fc_w[c,:] + fc_b[c]  (float4 loads)
    {
        float* s_yf = (float*)s_dlu[p];
        float p_[NCLS];
        #pragma unroll
        for (int c = 0; c < NCLS; ++c) p_[c] = 0.f;
        const float4* fw4 = (const float4*)fc_w;
        const float4* sf4 = (const float4*)s_bc[p];
        for (int q = tid8; q < 500; q += 256) {
            float4 f = sf4[q];
            #pragma unroll
            for (int c = 0; c < NCLS; ++c) {
                float4 wv = fw4[c * 500 + q];
                p_[c] += f.x * wv.x + f.y * wv.y + f.z * wv.z + f.w * wv.w;
            }
        }
        #pragma unroll
        for (int c = 0; c < NCLS; ++c) {
            float v = p_[c];
            v = dpp_add<0xB1>(v);
            v = dpp_add<0x4E>(v);
            v = dpp_add<0x141>(v);
            v = dpp_add<0x140>(v);
            v += __shfl_xor(v, 16);
            v += __shfl_xor(v, 32);
            p_[c] = v;
        }
        const int wave = tid8 >> 6;
        const int lane = tid8 & 63;
        __syncthreads();
        if (lane == 0) {
            #pragma unroll
            for (int c = 0; c < NCLS; ++c) s_yf[wave * NCLS + c] = p_[c];
        }
        __syncthreads();
        if (tid8 < NCLS) {
            float v = s_yf[tid8] + s_yf[NCLS + tid8] + s_yf[2 * NCLS + tid8] +
                      s_yf[3 * NCLS + tid8] + fc_b[tid8];
            out[(size_t)(b0 + p) * NCLS + tid8] = v;
        }
    }
}

extern "C" void kernel_launch(void* const* d_in, const int* in_sizes, int n_in,
                              void* d_out, int out_size, void* d_ws, size_t ws_size,
                              hipStream_t stream) {
    const float* x          = (const float*)d_in[0];
    const float* in_proj_w  = (const float*)d_in[1];
    const float* conv_w     = (const float*)d_in[2];
    const float* conv_b     = (const float*)d_in[3];
    const float* x_proj_w   = (const float*)d_in[4];
    const float* dt_proj_w  = (const float*)d_in[5];
    const float* dt_proj_b  = (const float*)d_in[6];
    const float* A_log      = (const float*)d_in[7];
    const float* Dp         = (const float*)d_in[8];
    const float* out_proj_w = (const float*)d_in[9];
    const float* fc_w       = (const float*)d_in[10];
    const float* fc_b       = (const float*)d_in[11];
    float* out = (float*)d_out;

    const int batch = in_sizes[0] / (8 * SEQ);  // 1024
    mamba_cls_kernel<<<batch / 2, 512, 0, stream>>>(
        x, in_proj_w, conv_w, conv_b, x_proj_w, dt_proj_w, dt_proj_b,
        A_log, Dp, out_proj_w, fc_w, fc_b, out);
}

// Round 14
// 53.378 us; speedup vs baseline: 1.0491x; 1.0491x over previous
//
#include <hip/hip_runtime.h>
#include <hip/hip_fp16.h>
#include <math.h>

#define SEQ 250
#define ST  252      // padded t-stride: rows 16B-aligned (ST*4 = 1008 = 63*16)
#define NCLS 12

typedef __attribute__((ext_vector_type(4))) _Float16 half4v;
typedef __attribute__((ext_vector_type(4))) float    float4v;

// Butterfly add via DPP (zero DS-pipe ops).
// 0xB1=quad_perm xor1; 0x4E=quad_perm xor2; 0x141=row_half_mirror (lane^7,
// valid once quad-constant); 0x140=row_mirror (lane^15, once 8-group-constant).
template<int CTRL>
__device__ __forceinline__ float dpp_add(float v) {
    int t = __builtin_amdgcn_update_dpp(0, __float_as_int(v), CTRL, 0xF, 0xF, true);
    return v + __int_as_float(t);
}

__device__ __forceinline__ __half2 f_as_h2(float f) {
    union { float f; __half2 h; } u; u.f = f; return u.h;
}
__device__ __forceinline__ float h2_as_f(__half2 h) {
    union { __half2 h; float f; } u; u.h = h; return u.f;
}

// 512 threads, TWO batch elements per block.
// LDS: 2 x (s_bc 16128 + s_dlu 16128 + s_sz 8064) = 80,640 B -> 2 blocks/CU.
// r4-r6: no register live ranges across the scan (spills -> 45 MB scratch).
// r11/r12: matrix pipe takes the x_proj projection (ph3).
// r13 lesson: ph1-MFMA + ph2-b128 regressed (gather overhead + cvt cost with
// only 4 waves of latency hiding) -> reverted to r12 scalar forms.
// r14: scan issues all 8 DS loads per 8t up front; y-writes as masked b128.
__global__ __launch_bounds__(512)
void mamba_cls_kernel(
    const float* __restrict__ x,         // (B, 8, 250)
    const float* __restrict__ in_proj_w, // (32, 8)
    const float* __restrict__ conv_w,    // (16, 4)
    const float* __restrict__ conv_b,    // (16)
    const float* __restrict__ x_proj_w,  // (33, 16)
    const float* __restrict__ dt_proj_w, // (16, 1)
    const float* __restrict__ dt_proj_b, // (16)
    const float* __restrict__ A_log,     // (16, 16)
    const float* __restrict__ Dp,        // (16)
    const float* __restrict__ out_proj_w,// (8, 16)
    const float* __restrict__ fc_w,      // (12, 2000)
    const float* __restrict__ fc_b,      // (12)
    float* __restrict__ out)             // (B, 12)
{
    // Per problem p:
    // s_bc [p]: ph1-2 x_in (f32 view [d*ST+t]); ph3+ {B,C} half2 [s*ST+t];
    //           ph5b+ out2000 (f32 view [t*8+j])
    // s_dlu   : ph0-1 staged x of BOTH problems (flat f32 from s_dlu[0]);
    //           ph2+ {dl,u} half2 [d*ST+t] (u=.y ph2, dl=.x ph3);
    //           ph4+ y (f32, same word); ph6 reduce partials
    // s_sz [p]: silu(z) fp16 [d*ST+t]
    __shared__ __align__(16) __half2 s_bc [2][16 * ST];
    __shared__ __align__(16) __half2 s_dlu[2][16 * ST];
    __shared__ __align__(16) __half  s_sz [2][16 * ST];

    const int tid  = threadIdx.x;
    const int p    = tid >> 8;
    const int tid8 = tid & 255;
    const int b0   = blockIdx.x * 2;

    // ---- Phase 0: stage x for BOTH problems coalesced (float4)
    {
        float4* s_xf4 = (float4*)s_dlu[0];
        const float4* __restrict__ xb4 =
            (const float4*)(x + (size_t)b0 * (8 * SEQ));
        for (int i = tid; i < 1000; i += 512) s_xf4[i] = xb4[i];
    }
    __syncthreads();

    // ---- Phase 1: x_in[d*ST+t] -> s_bc(f32) ; silu(z) -> s_sz   (r12 form)
    {
        float* s_f  = (float*)s_bc[p];
        const float* s_xf = (const float*)s_dlu[0] + p * (8 * SEQ);
        const int d  = tid8 & 15;
        const int t0 = tid8 >> 4;
        float w1[8], w2[8];
        #pragma unroll
        for (int m = 0; m < 8; ++m) {
            w1[m] = in_proj_w[d * 8 + m];
            w2[m] = in_proj_w[(16 + d) * 8 + m];
        }
        #pragma unroll
        for (int i = 0; i < 16; ++i) {
            int t = t0 + i * 16;
            if (t < SEQ) {
                float acc = 0.f, z = 0.f;
                #pragma unroll
                for (int m = 0; m < 8; ++m) {
                    float xv = s_xf[m * SEQ + t];
                    acc = fmaf(w1[m], xv, acc);
                    z   = fmaf(w2[m], xv, z);
                }
                s_f[d * ST + t] = acc;
                s_sz[p][d * ST + t] = __float2half(z / (1.f + __expf(-z)));
            }
        }
    }
    __syncthreads();

    // ---- Phase 2: causal conv(k=4)+SiLU -> u into s_dlu[p][d*ST+t].y (r12)
    {
        const float* s_f = (const float*)s_bc[p];
        const int d  = tid8 & 15;
        const int t0 = tid8 >> 4;
        float cw[4];
        #pragma unroll
        for (int k = 0; k < 4; ++k) cw[k] = conv_w[d * 4 + k];
        const float cb = conv_b[d];
        #pragma unroll
        for (int i = 0; i < 16; ++i) {
            int t = t0 + i * 16;
            if (t < SEQ) {
                float acc = cb;
                #pragma unroll
                for (int k = 0; k < 4; ++k) {
                    int tt = t + k - 3;
                    if (tt >= 0) acc = fmaf(cw[k], s_f[d * ST + tt], acc);
                }
                float sg = 1.f / (1.f + __expf(-acc));
                s_dlu[p][d * ST + t].y = __float2half(acc * sg);
            }
        }
    }
    __syncthreads();

    // ---- Phase 3 (MFMA): per 16-t tile, D = u(16t x 16d) * W(16d x 16col)
    // via v_mfma_f32_16x16x16f16 (fragment map verified r12).
    {
        const int wave = tid8 >> 6;       // 0..3
        const int l    = tid8 & 63;
        const int rowc = l & 15;          // A-row (t_local) AND D-col (state)
        const int kg   = l >> 4;          // k-group

        half4v wB, wC, wD;
        #pragma unroll
        for (int i = 0; i < 4; ++i) {
            wB[i] = (_Float16)x_proj_w[(1  + rowc) * 16 + 4 * kg + i];
            wC[i] = (_Float16)x_proj_w[(17 + rowc) * 16 + 4 * kg + i];
            wD[i] = (_Float16)x_proj_w[4 * kg + i];
        }
        const float dtw_c = dt_proj_w[rowc];
        const float dtb_c = dt_proj_b[rowc];
        const float4v zero4 = {0.f, 0.f, 0.f, 0.f};
        const unsigned int* __restrict__ dlu_w = (const unsigned int*)s_dlu[p];

        for (int tile = wave; tile < 16; tile += 4) {
            const int t0 = tile * 16;
            // A-frag: u[t0+rowc][4kg+i] = high half of {dl,u} word
            unsigned int w0 = dlu_w[(4 * kg + 0) * ST + t0 + rowc];
            unsigned int w1 = dlu_w[(4 * kg + 1) * ST + t0 + rowc];
            unsigned int w2 = dlu_w[(4 * kg + 2) * ST + t0 + rowc];
            unsigned int w3 = dlu_w[(4 * kg + 3) * ST + t0 + rowc];
            union { unsigned int u[2]; half4v h; } A;
            A.u[0] = (w0 >> 16) | (w1 & 0xFFFF0000u);
            A.u[1] = (w2 >> 16) | (w3 & 0xFFFF0000u);

            float4v dB = __builtin_amdgcn_mfma_f32_16x16x16f16(A.h, wB, zero4, 0, 0, 0);
            float4v dC = __builtin_amdgcn_mfma_f32_16x16x16f16(A.h, wC, zero4, 0, 0, 0);
            float4v dT = __builtin_amdgcn_mfma_f32_16x16x16f16(A.h, wD, zero4, 0, 0, 0);

            const int tb = t0 + kg * 4;   // first of this lane's 4 t's
            if (tb <= 248) {              // words tb..tb+3 <= 251 (pad ok)
                __half2 h0 = __floats2half2_rn(dB[0], dC[0]);
                __half2 h1 = __floats2half2_rn(dB[1], dC[1]);
                __half2 h2 = __floats2half2_rn(dB[2], dC[2]);
                __half2 h3 = __floats2half2_rn(dB[3], dC[3]);
                float4 wv;
                wv.x = h2_as_f(h0); wv.y = h2_as_f(h1);
                wv.z = h2_as_f(h2); wv.w = h2_as_f(h3);
                *reinterpret_cast<float4*>(s_bc[p] + rowc * ST + tb) = wv;
            }
            #pragma unroll
            for (int r = 0; r < 4; ++r) {
                int t = tb + r;
                if (t < SEQ) {
                    float v  = fmaf(dT[r], dtw_c, dtb_c);
                    float dl = (v > 20.f) ? v : __logf(1.f + __expf(v));
                    s_dlu[p][rowc * ST + t].x = __float2half(dl);
                }
            }
        }
    }
    __syncthreads();

    // ---- Phase 4: scan, s-folded x2, 8t batches: all 8 DS loads issue up
    // front (one lgkm region per 8t); y accumulated into float4 and written
    // as ONE masked b128 store per 4t. Active: tid<256 (waves 0-3).
    if (tid < 256) {
        const int sp   = tid >> 7;
        const int i7   = tid & 127;
        const int d    = i7 >> 3;
        const int s2   = i7 & 7;
        const float A2a = -__expf(A_log[d * 16 + s2])     * 1.4426950408889634f;
        const float A2b = -__expf(A_log[d * 16 + s2 + 8]) * 1.4426950408889634f;
        const float Dd  = Dp[d];
        const __half2* __restrict__ dlu_p = s_dlu[sp] + d * ST;
        const __half2* __restrict__ bca_p = s_bc [sp] + s2 * ST;
        const __half2* __restrict__ bcb_p = s_bc [sp] + (s2 + 8) * ST;
        const __half*  __restrict__ sz_p  = (const __half*)s_sz[sp] + d * ST;
        float* __restrict__ y_p = (float*)s_dlu[sp] + d * ST;
        float ha = 0.f, hb = 0.f;
        for (int t = 0; t < 248; t += 8) {
            // batched loads for 8 timesteps
            float4 du_a = *reinterpret_cast<const float4*>(dlu_p + t);
            float4 du_b = *reinterpret_cast<const float4*>(dlu_p + t + 4);
            float4 ba_a = *reinterpret_cast<const float4*>(bca_p + t);
            float4 ba_b = *reinterpret_cast<const float4*>(bca_p + t + 4);
            float4 bb_a = *reinterpret_cast<const float4*>(bcb_p + t);
            float4 bb_b = *reinterpret_cast<const float4*>(bcb_p + t + 4);
            float2 sza  = *reinterpret_cast<const float2*>(sz_p + t);
            float2 szb  = *reinterpret_cast<const float2*>(sz_p + t + 4);

            float fdu[8] = {du_a.x, du_a.y, du_a.z, du_a.w,
                            du_b.x, du_b.y, du_b.z, du_b.w};
            float fba[8] = {ba_a.x, ba_a.y, ba_a.z, ba_a.w,
                            ba_b.x, ba_b.y, ba_b.z, ba_b.w};
            float fbb[8] = {bb_a.x, bb_a.y, bb_a.z, bb_a.w,
                            bb_b.x, bb_b.y, bb_b.z, bb_b.w};
            float2 s0 = __half22float2(f_as_h2(sza.x));
            float2 s1 = __half22float2(f_as_h2(sza.y));
            float2 s2f = __half22float2(f_as_h2(szb.x));
            float2 s3 = __half22float2(f_as_h2(szb.y));
            float fsz[8] = {s0.x, s0.y, s1.x, s1.y, s2f.x, s2f.y, s3.x, s3.y};

            float yv[8];
            #pragma unroll
            for (int tt = 0; tt < 8; ++tt) {
                float2 du  = __half22float2(f_as_h2(fdu[tt]));
                float2 bca = __half22float2(f_as_h2(fba[tt]));
                float2 bcb = __half22float2(f_as_h2(fbb[tt]));
                float dlu = du.x * du.y;
                ha = fmaf(exp2f(du.x * A2a), ha, dlu * bca.x);
                hb = fmaf(exp2f(du.x * A2b), hb, dlu * bcb.x);
                float r = fmaf(hb, bcb.y, ha * bca.y);
                r = dpp_add<0xB1>(r);
                r = dpp_add<0x4E>(r);
                r = dpp_add<0x141>(r);
                yv[tt] = fmaf(du.y, Dd, r) * fsz[tt];
            }
            if (s2 == 0) {
                float4 y4;
                y4.x = yv[0]; y4.y = yv[1]; y4.z = yv[2]; y4.w = yv[3];
                *reinterpret_cast<float4*>(y_p + t) = y4;
                y4.x = yv[4]; y4.y = yv[5]; y4.z = yv[6]; y4.w = yv[7];
                *reinterpret_cast<float4*>(y_p + t + 4) = y4;
            }
        }
        {   // tail t = 248, 249
            float2 duv2 = *reinterpret_cast<const float2*>(dlu_p + 248);
            float2 bca2 = *reinterpret_cast<const float2*>(bca_p + 248);
            float2 bcb2 = *reinterpret_cast<const float2*>(bcb_p + 248);
            float2 szf  = __half22float2(*reinterpret_cast<const __half2*>(sz_p + 248));
            float fdu[2] = {duv2.x, duv2.y};
            float fba[2] = {bca2.x, bca2.y};
            float fbb[2] = {bcb2.x, bcb2.y};
            float fsz[2] = {szf.x, szf.y};
            float yv[2];
            #pragma unroll
            for (int tt = 0; tt < 2; ++tt) {
                float2 du  = __half22float2(f_as_h2(fdu[tt]));
                float2 bca = __half22float2(f_as_h2(fba[tt]));
                float2 bcb = __half22float2(f_as_h2(fbb[tt]));
                float dlu = du.x * du.y;
                ha = fmaf(exp2f(du.x * A2a), ha, dlu * bca.x);
                hb = fmaf(exp2f(du.x * A2b), hb, dlu * bcb.x);
                float r = fmaf(hb, bcb.y, ha * bca.y);
                r = dpp_add<0xB1>(r);
                r = dpp_add<0x4E>(r);
                r = dpp_add<0x141>(r);
                yv[tt] = fmaf(du.y, Dd, r) * fsz[tt];
            }
            if (s2 == 0) {
                float2 y2; y2.x = yv[0]; y2.y = yv[1];
                *reinterpret_cast<float2*>(y_p + 248) = y2;
            }
        }
    }
    __syncthreads();

    // ---- Phase 5b: out2000[t*8+j] = sum_d y[d,t]*out_proj_w[j,d]
    // Mapping: j = tid8&7, 4t-chunk = tid8>>3; y read as b128 per d-row.
    {
        float* s_f  = (float*)s_bc[p];
        const float* s_yf = (const float*)s_dlu[p];
        const int j = tid8 & 7;
        float w[16];
        #pragma unroll
        for (int d2 = 0; d2 < 16; ++d2) w[d2] = out_proj_w[j * 16 + d2];
        for (int t0 = (tid8 >> 3) * 4; t0 < SEQ; t0 += 128) {
            float a0 = 0.f, a1 = 0.f, a2 = 0.f, a3 = 0.f;
            #pragma unroll
            for (int d2 = 0; d2 < 16; ++d2) {
                float4 y4 = *reinterpret_cast<const float4*>(s_yf + d2 * ST + t0);
                a0 = fmaf(w[d2], y4.x, a0);
                a1 = fmaf(w[d2], y4.y, a1);
                a2 = fmaf(w[d2], y4.z, a2);
                a3 = fmaf(w[d2], y4.w, a3);
            }
            s_f[(t0 + 0) * 8 + j] = a0;
            s_f[(t0 + 1) * 8 + j] = a1;
            if (t0 + 2 < SEQ) s_f[(t0 + 2) * 8 + j] = a2;
            if (t0 + 3 < SEQ) s_f[(t0 + 3) * 8 + j] = a3;
        }
    }
    __syncthreads();

    // ---- Phase 6: logits[c] = out2000 . fc_w[c,:] + fc_b[c]  (float4 loads)
    {
        float* s_yf = (float*)s_dlu[p];
        float p_[NCLS];
        #pragma unroll
        for (int c = 0; c < NCLS; ++c) p_[c] = 0.f;
        const float4* fw4 = (const float4*)fc_w;
        const float4* sf4 = (const float4*)s_bc[p];
        for (int q = tid8; q < 500; q += 256) {
            float4 f = sf4[q];
            #pragma unroll
            for (int c = 0; c < NCLS; ++c) {
                float4 wv = fw4[c * 500 + q];
                p_[c] += f.x * wv.x + f.y * wv.y + f.z * wv.z + f.w * wv.w;
            }
        }
        #pragma unroll
        for (int c = 0; c < NCLS; ++c) {
            float v = p_[c];
            v = dpp_add<0xB1>(v);
            v = dpp_add<0x4E>(v);
            v = dpp_add<0x141>(v);
            v = dpp_add<0x140>(v);
            v += __shfl_xor(v, 16);
            v += __shfl_xor(v, 32);
            p_[c] = v;
        }
        const int wave = tid8 >> 6;
        const int lane = tid8 & 63;
        __syncthreads();
        if (lane == 0) {
            #pragma unroll
            for (int c = 0; c < NCLS; ++c) s_yf[wave * NCLS + c] = p_[c];
        }
        __syncthreads();
        if (tid8 < NCLS) {
            float v = s_yf[tid8] + s_yf[NCLS + tid8] + s_yf[2 * NCLS + tid8] +
                      s_yf[3 * NCLS + tid8] + fc_b[tid8];
            out[(size_t)(b0 + p) * NCLS + tid8] = v;
        }
    }
}

extern "C" void kernel_launch(void* const* d_in, const int* in_sizes, int n_in,
                              void* d_out, int out_size, void* d_ws, size_t ws_size,
                              hipStream_t stream) {
    const float* x          = (const float*)d_in[0];
    const float* in_proj_w  = (const float*)d_in[1];
    const float* conv_w     = (const float*)d_in[2];
    const float* conv_b     = (const float*)d_in[3];
    const float* x_proj_w   = (const float*)d_in[4];
    const float* dt_proj_w  = (const float*)d_in[5];
    const float* dt_proj_b  = (const float*)d_in[6];
    const float* A_log      = (const float*)d_in[7];
    const float* Dp         = (const float*)d_in[8];
    const float* out_proj_w = (const float*)d_in[9];
    const float* fc_w       = (const float*)d_in[10];
    const float* fc_b       = (const float*)d_in[11];
    float* out = (float*)d_out;

    const int batch = in_sizes[0] / (8 * SEQ);  // 1024
    mamba_cls_kernel<<<batch / 2, 512, 0, stream>>>(
        x, in_proj_w, conv_w, conv_b, x_proj_w, dt_proj_w, dt_proj_b,
        A_log, Dp, out_proj_w, fc_w, fc_b, out);
}